// Round 9
// baseline (1620.375 us; speedup 1.0000x reference)
//
#include <hip/hip_runtime.h>

#define B_ 4
#define H_ 256
#define W_ 256
#define PXF4 9   // float4 per pixel row in LDS: 8 data + 1 pad (144 B stride)

// ================= main kernel: 32x16 tile, 512 threads, 1 px/thread, pipelined ============
#define TSX 32
#define TSY 16
#define TWX 40
#define TWY 24
#define NPX (TWX * TWY)   // 960

struct Signs { unsigned long long p0, n0; unsigned int p1, n1; };

// f32 dot of 32-register array vs one pixel row held in 8 float4 regs.
// NOTE: numerics-load-bearing — accumulation structure verified (absmax 12.625).
__device__ __forceinline__ float dot32q(const float* a, const float4* q) {
    float s0 = 0.f, s1 = 0.f, s2 = 0.f, s3 = 0.f;
#pragma unroll
    for (int u = 0; u < 8; ++u) {
        float4 v = q[u];
        s0 += a[4*u+0] * v.x; s1 += a[4*u+1] * v.y;
        s2 += a[4*u+2] * v.z; s3 += a[4*u+3] * v.w;
    }
    return (s0 + s1) + (s2 + s3);
}

__device__ __forceinline__ void loadq(float4* q, const float4* src) {
#pragma unroll
    for (int u = 0; u < 8; ++u) q[u] = src[u];
}

// NOTE: no min-waves-per-EU arg! (512,2) capped VGPR at 128 -> 2.98 GB scratch spill (R8);
// (1024,4) capped at 64 -> 32 GB spill (R7). LDS caps occupancy at 1 block/CU regardless,
// so the hint buys nothing. Plain (512) -> cap 256, pipelined state (~190) fits.
__global__ void __launch_bounds__(512)
gocorP(const float* __restrict__ rf_g,
       const float* __restrict__ beta_p, const float* __restrict__ tw_p,
       const float* __restrict__ sw_p,  const float* __restrict__ mw_p,
       const float* __restrict__ mrw_p, const float* __restrict__ mrb_p,
       const float* __restrict__ lrw_p, const float* __restrict__ lrb_p,
       const float* __restrict__ wreg_p, const float* __restrict__ lsl_p,
       float* __restrict__ out)
{
    extern __shared__ float4 smem[];
    float4* s_rf   = smem;                    // NPX * PXF4  (138,240 B)
    float4* s_kp   = smem + NPX * PXF4;       // 81
    float*  s_bias = (float*)(s_kp + 81);     // [0..32) mr_b, [32..64) lr_b

    const int tid = threadIdx.x;
    const int tx = tid & 31, ty = tid >> 5;   // 32 x 16 pixels
    const int bx = blockIdx.x * TSX, by = blockIdx.y * TSY, bb = blockIdx.z;
    const float* rfb = rf_g + (size_t)bb * H_ * W_ * 32;

    // ---- stage f32 rf tile (+halo), zero outside image ----
    for (int idx = tid; idx < NPX * 8; idx += 512) {
        int u = idx & 7, p = idx >> 3;
        int ly = p / TWX, lx = p - ly * TWX;
        int gy = by + ly - 4, gx = bx + lx - 4;
        float4 v = make_float4(0.f, 0.f, 0.f, 0.f);
        if (gy >= 0 && gy < H_ && gx >= 0 && gx < W_)
            v = *(const float4*)(rfb + ((size_t)(gy * W_ + gx)) * 32 + u * 4);
        s_rf[p * PXF4 + u] = v;
    }

    // ---- per-block activation params (f32, faithful to reference) ----
    if (tid < 81) {
        int i = tid / 9, j = tid % 9;
        float di = (float)(i - 4), dj = (float)(j - 4);
        float dist = sqrtf(di * di + dj * dj);
        float y = 0.f, vp = 0.f, m = 0.f;
        for (int b = 0; b < 10; ++b) {
            float bd = 2.f * dist - (float)b;
            float val;
            if (i < 8) val = fmaxf(0.f, 1.f - fabsf(bd));        // triangular rows 0..7
            else       val = fminf(1.f, fmaxf(0.f, 1.f + bd));   // clipped row 8 (faithful)
            y  += val * tw_p[b];
            vp += val * sw_p[b];
            m  += val * mw_p[b];
        }
        float wm = 1.f / (1.f + expf(-m));
        s_kp[tid] = make_float4(vp * 0.5f * (1.f - wm),
                                vp * 0.5f * (1.f + wm),
                                vp * y, 0.f);
    }
    if (tid < 32)      s_bias[tid] = mrb_p[tid];
    else if (tid < 64) s_bias[tid] = lrb_p[tid - 32];

    float beta = beta_p[0];
    float wr   = wreg_p[0];
    float regw = fmaxf(wr * wr, (1e-5f * 1e-5f) / (32.f * 32.f));
    float step = expf(lsl_p[0]);

    __syncthreads();

    // ---- init: w = beta * rf / (mean(rf^2) + 1e-6) ----
    float w[32];
    {
        const float4* r = &s_rf[(((ty + 4) * TWX) + (tx + 4)) * PXF4];
        float4 q[8];
        loadq(q, r);
#pragma unroll
        for (int u = 0; u < 8; ++u) {
            w[4*u+0] = q[u].x; w[4*u+1] = q[u].y; w[4*u+2] = q[u].z; w[4*u+3] = q[u].w;
        }
        float msq = 0.f;
#pragma unroll
        for (int c = 0; c < 32; ++c) msq += w[c] * w[c];
        float inv = beta / (msq * (1.f / 32.f) + 1e-6f);
#pragma unroll
        for (int c = 0; c < 32; ++c) w[c] *= inv;
    }

    float mp[32], fg[32];

    for (int it = 0; it < 3; ++it) {
        // ============ Phase A: c_k -> s = dact*res; mp += s*mr_w[k]; record sign ============
        Signs sg{0ull, 0ull, 0u, 0u};
#pragma unroll
        for (int c = 0; c < 32; ++c) mp[c] = s_bias[c];

        for (int i = 0; i < 9; ++i) {
            const float4* rowp = &s_rf[((ty + i) * TWX + tx) * PXF4];
            const int kbase = i * 9;
            float4 qa[8], qb[8];
            loadq(qa, rowp);

            auto stepA = [&](int k, const float4* q) {
                float ck = dot32q(w, q) * (1.f / 32.f);
                if (ck > 0.f)      { if (k < 64) sg.p0 |= 1ull << k; else sg.p1 |= 1u << (k - 64); }
                else if (ck < 0.f) { if (k < 64) sg.n0 |= 1ull << k; else sg.n1 |= 1u << (k - 64); }
                float4 kp = s_kp[k];
                float sn = (ck > 0.f) ? 1.f : ((ck < 0.f) ? -1.f : 0.f);
                float act  = kp.x * fabsf(ck) + kp.y * ck;
                float res  = act - kp.z;
                float dact = kp.x * sn + kp.y;
                float s = dact * res;
                const float* mr = mrw_p + k * 32;   // wave-uniform -> s_load, K$-hot
#pragma unroll
                for (int c = 0; c < 32; ++c) mp[c] += s * mr[c];
            };

#pragma unroll
            for (int jj = 0; jj < 4; ++jj) {
                loadq(qb, rowp + (2 * jj + 1) * PXF4);
                stepA(kbase + 2 * jj, qa);
                loadq(qa, rowp + (2 * jj + 2) * PXF4);
                stepA(kbase + 2 * jj + 1, qb);
            }
            stepA(kbase + 8, qa);
        }

        // ============ Phase B: fg = lr_b + regw*w + sum_k (dot(mp,r_k)/32) * lr_w[k] ============
#pragma unroll
        for (int c = 0; c < 32; ++c) fg[c] = s_bias[32 + c] + regw * w[c];

        for (int i = 0; i < 9; ++i) {
            const float4* rowp = &s_rf[((ty + i) * TWX + tx) * PXF4];
            const int kbase = i * 9;
            float4 qa[8], qb[8];
            loadq(qa, rowp);

            auto stepB = [&](int k, const float4* q) {
                float ck = dot32q(mp, q) * (1.f / 32.f);
                const float* lr = lrw_p + k * 32;   // wave-uniform -> s_load
#pragma unroll
                for (int c = 0; c < 32; ++c) fg[c] += ck * lr[c];
            };

#pragma unroll
            for (int jj = 0; jj < 4; ++jj) {
                loadq(qb, rowp + (2 * jj + 1) * PXF4);
                stepB(kbase + 2 * jj, qa);
                loadq(qa, rowp + (2 * jj + 2) * PXF4);
                stepB(kbase + 2 * jj + 1, qb);
            }
            stepB(kbase + 8, qa);
        }

        // ============ Phase C: alpha = sum(fg^2)/sum((dact*dot(fg,r_k)/32)^2) ============
        float num = 0.f;
#pragma unroll
        for (int c = 0; c < 32; ++c) num += fg[c] * fg[c];
        float den = 0.f;

        for (int i = 0; i < 9; ++i) {
            const float4* rowp = &s_rf[((ty + i) * TWX + tx) * PXF4];
            const int kbase = i * 9;
            float4 qa[8], qb[8];
            loadq(qa, rowp);

            auto stepC = [&](int k, const float4* q) {
                float c3 = dot32q(fg, q) * (1.f / 32.f);
                bool bp = (k < 64) ? ((sg.p0 >> k) & 1ull) : ((sg.p1 >> (k - 64)) & 1u);
                bool bn = (k < 64) ? ((sg.n0 >> k) & 1ull) : ((sg.n1 >> (k - 64)) & 1u);
                float sn = bp ? 1.f : (bn ? -1.f : 0.f);
                float4 kp = s_kp[k];
                float dact = kp.x * sn + kp.y;
                float s3 = dact * c3;
                den += s3 * s3;
            };

#pragma unroll
            for (int jj = 0; jj < 4; ++jj) {
                loadq(qb, rowp + (2 * jj + 1) * PXF4);
                stepC(kbase + 2 * jj, qa);
                loadq(qa, rowp + (2 * jj + 2) * PXF4);
                stepC(kbase + 2 * jj + 1, qb);
            }
            stepC(kbase + 8, qa);
        }

        float as = (num / den) * step;
#pragma unroll
        for (int c = 0; c < 32; ++c) w[c] += as * fg[c];
    }

    // ---- f32 output, coalesced float4 stores ----
    float* o = out + (((size_t)bb * H_ + (by + ty)) * W_ + (bx + tx)) * 32;
#pragma unroll
    for (int u = 0; u < 8; ++u)
        *(float4*)(o + u * 4) = make_float4(w[4*u+0], w[4*u+1], w[4*u+2], w[4*u+3]);
}

// ================= fallback: 1 px/thread, 16x8 tile, 128 threads (R4-proven) =============
__device__ __forceinline__ float dot32f(const float* a, const float4* r) {
    float s0 = 0.f, s1 = 0.f, s2 = 0.f, s3 = 0.f;
#pragma unroll
    for (int u = 0; u < 8; ++u) {
        float4 q = r[u];
        s0 += a[4*u+0] * q.x; s1 += a[4*u+1] * q.y;
        s2 += a[4*u+2] * q.z; s3 += a[4*u+3] * q.w;
    }
    return (s0 + s1) + (s2 + s3);
}

__global__ void __launch_bounds__(128)
gocor1(const float* __restrict__ rf_g,
       const float* __restrict__ beta_p, const float* __restrict__ tw_p,
       const float* __restrict__ sw_p,  const float* __restrict__ mw_p,
       const float* __restrict__ mrw_p, const float* __restrict__ mrb_p,
       const float* __restrict__ lrw_p, const float* __restrict__ lrb_p,
       const float* __restrict__ wreg_p, const float* __restrict__ lsl_p,
       float* __restrict__ out)
{
    constexpr int TWXc = 24, NPXc = 24 * 16;
    extern __shared__ float4 smem[];
    float4* s_rf  = smem;
    float4* s_kp  = smem + NPXc * PXF4;
    float*  s_bias = (float*)(s_kp + 81);

    const int tid = threadIdx.x;
    const int tx = tid & 15, ty = tid >> 4;
    const int bx = blockIdx.x * 16, by = blockIdx.y * 8, bb = blockIdx.z;
    const float* rfb = rf_g + (size_t)bb * H_ * W_ * 32;

    for (int idx = tid; idx < NPXc * 8; idx += 128) {
        int u = idx & 7, p = idx >> 3;
        int ly = p / TWXc, lx = p - ly * TWXc;
        int gy = by + ly - 4, gx = bx + lx - 4;
        float4 v = make_float4(0.f, 0.f, 0.f, 0.f);
        if (gy >= 0 && gy < H_ && gx >= 0 && gx < W_)
            v = *(const float4*)(rfb + ((size_t)(gy * W_ + gx)) * 32 + u * 4);
        s_rf[p * PXF4 + u] = v;
    }
    if (tid < 81) {
        int i = tid / 9, j = tid % 9;
        float di = (float)(i - 4), dj = (float)(j - 4);
        float dist = sqrtf(di * di + dj * dj);
        float y = 0.f, vp = 0.f, m = 0.f;
        for (int b = 0; b < 10; ++b) {
            float bd = 2.f * dist - (float)b;
            float val = (i < 8) ? fmaxf(0.f, 1.f - fabsf(bd))
                                : fminf(1.f, fmaxf(0.f, 1.f + bd));
            y += val * tw_p[b]; vp += val * sw_p[b]; m += val * mw_p[b];
        }
        float wm = 1.f / (1.f + expf(-m));
        s_kp[tid] = make_float4(vp * 0.5f * (1.f - wm), vp * 0.5f * (1.f + wm), vp * y, 0.f);
    }
    if (tid < 32)      s_bias[tid] = mrb_p[tid];
    else if (tid < 64) s_bias[tid] = lrb_p[tid - 32];

    float beta = beta_p[0], wr = wreg_p[0];
    float regw = fmaxf(wr * wr, (1e-5f * 1e-5f) / (32.f * 32.f));
    float step = expf(lsl_p[0]);
    __syncthreads();

    float w[32];
    {
        const float4* r = &s_rf[(((ty + 4) * TWXc) + (tx + 4)) * PXF4];
#pragma unroll
        for (int u = 0; u < 8; ++u) {
            float4 q = r[u];
            w[4*u+0] = q.x; w[4*u+1] = q.y; w[4*u+2] = q.z; w[4*u+3] = q.w;
        }
        float msq = 0.f;
#pragma unroll
        for (int c = 0; c < 32; ++c) msq += w[c] * w[c];
        float inv = beta / (msq * (1.f / 32.f) + 1e-6f);
#pragma unroll
        for (int c = 0; c < 32; ++c) w[c] *= inv;
    }

    float mp[32], fg[32];
    for (int it = 0; it < 3; ++it) {
        Signs sg{0ull, 0ull, 0u, 0u};
#pragma unroll
        for (int c = 0; c < 32; ++c) mp[c] = s_bias[c];
        for (int i = 0; i < 9; ++i) {
            int rowbase = (ty + i) * TWXc + tx;
            for (int j = 0; j < 9; ++j) {
                int k = i * 9 + j;
                float ck = dot32f(w, &s_rf[(rowbase + j) * PXF4]) * (1.f / 32.f);
                if (ck > 0.f)      { if (k < 64) sg.p0 |= 1ull << k; else sg.p1 |= 1u << (k - 64); }
                else if (ck < 0.f) { if (k < 64) sg.n0 |= 1ull << k; else sg.n1 |= 1u << (k - 64); }
                float4 kp = s_kp[k];
                float sn = (ck > 0.f) ? 1.f : ((ck < 0.f) ? -1.f : 0.f);
                float s = (kp.x * sn + kp.y) * ((kp.x * fabsf(ck) + kp.y * ck) - kp.z);
                const float* mr = mrw_p + k * 32;
#pragma unroll
                for (int c = 0; c < 32; ++c) mp[c] += s * mr[c];
            }
        }
#pragma unroll
        for (int c = 0; c < 32; ++c) fg[c] = s_bias[32 + c] + regw * w[c];
        for (int i = 0; i < 9; ++i) {
            int rowbase = (ty + i) * TWXc + tx;
            for (int j = 0; j < 9; ++j) {
                float ck = dot32f(mp, &s_rf[(rowbase + j) * PXF4]) * (1.f / 32.f);
                const float* lr = lrw_p + (i * 9 + j) * 32;
#pragma unroll
                for (int c = 0; c < 32; ++c) fg[c] += ck * lr[c];
            }
        }
        float num = 0.f;
#pragma unroll
        for (int c = 0; c < 32; ++c) num += fg[c] * fg[c];
        float den = 0.f;
        for (int i = 0; i < 9; ++i) {
            int rowbase = (ty + i) * TWXc + tx;
            for (int j = 0; j < 9; ++j) {
                int k = i * 9 + j;
                float c3 = dot32f(fg, &s_rf[(rowbase + j) * PXF4]) * (1.f / 32.f);
                bool bp = (k < 64) ? ((sg.p0 >> k) & 1ull) : ((sg.p1 >> (k - 64)) & 1u);
                bool bn = (k < 64) ? ((sg.n0 >> k) & 1ull) : ((sg.n1 >> (k - 64)) & 1u);
                float sn = bp ? 1.f : (bn ? -1.f : 0.f);
                float4 kp = s_kp[k];
                float s3 = (kp.x * sn + kp.y) * c3;
                den += s3 * s3;
            }
        }
        float as = (num / den) * step;
#pragma unroll
        for (int c = 0; c < 32; ++c) w[c] += as * fg[c];
    }
    float* o = out + (((size_t)bb * H_ + (by + ty)) * W_ + (bx + tx)) * 32;
#pragma unroll
    for (int u = 0; u < 8; ++u)
        *(float4*)(o + u * 4) = make_float4(w[4*u+0], w[4*u+1], w[4*u+2], w[4*u+3]);
}

static const size_t BIG_SHM   = (size_t)(NPX * PXF4 + 81 + 16) * 16;     // 139,792 B
static const size_t SMALL_SHM = (size_t)(24 * 16 * PXF4 + 81 + 16) * 16; //  56,848 B

static bool query_big_path() {
    int dev = 0;
    if (hipGetDevice(&dev) != hipSuccess) return false;
    hipFuncSetAttribute(reinterpret_cast<const void*>(&gocorP),
                        hipFuncAttributeMaxDynamicSharedMemorySize, (int)BIG_SHM);
    int maxShm = 0;
    if (hipDeviceGetAttribute(&maxShm, hipDeviceAttributeMaxSharedMemoryPerBlock, dev) == hipSuccess &&
        (size_t)maxShm >= BIG_SHM)
        return true;
    hipFuncAttributes fa;
    if (hipFuncGetAttributes(&fa, reinterpret_cast<const void*>(&gocorP)) == hipSuccess &&
        (size_t)fa.maxDynamicSharedSizeBytes >= BIG_SHM)
        return true;
    return false;
}

extern "C" void kernel_launch(void* const* d_in, const int* in_sizes, int n_in,
                              void* d_out, int out_size, void* d_ws, size_t ws_size,
                              hipStream_t stream) {
    (void)d_ws; (void)ws_size; (void)in_sizes; (void)n_in; (void)out_size;
    static const bool use_big = query_big_path();   // resolved before graph capture

    const float* rf   = (const float*)d_in[0];
    const float* beta = (const float*)d_in[2];
    const float* tw   = (const float*)d_in[3];
    const float* sw   = (const float*)d_in[4];
    const float* mw   = (const float*)d_in[5];
    const float* mrw  = (const float*)d_in[6];
    const float* mrb  = (const float*)d_in[7];
    const float* lrw  = (const float*)d_in[8];
    const float* lrb  = (const float*)d_in[9];
    const float* wreg = (const float*)d_in[10];
    const float* lsl  = (const float*)d_in[11];
    float* o = (float*)d_out;

    if (use_big) {
        dim3 grid(W_ / TSX, H_ / TSY, B_);
        hipLaunchKernelGGL(gocorP, grid, dim3(512), BIG_SHM, stream,
                           rf, beta, tw, sw, mw, mrw, mrb, lrw, lrb, wreg, lsl, o);
    } else {
        dim3 grid(W_ / 16, H_ / 8, B_);
        hipLaunchKernelGGL(gocor1, grid, dim3(128), SMALL_SHM, stream,
                           rf, beta, tw, sw, mw, mrw, mrb, lrw, lrb, wreg, lsl, o);
    }
}